// Round 1
// baseline (4709.216 us; speedup 1.0000x reference)
//
#include <hip/hip_runtime.h>
#include <hip/hip_bf16.h>

#define HD 128
#define ED 16
#define TD 32

__device__ __forceinline__ float siluf(float v){ return v * (1.0f / (1.0f + __expf(-v))); }

// bf16 pack/unpack helpers (RTN)
__device__ __forceinline__ unsigned int bfbits(float x){
  unsigned int a = __float_as_uint(x);
  return (a + 0x7fffu + ((a >> 16) & 1u)) >> 16;
}
__device__ __forceinline__ unsigned int packbf(float lo, float hi){
  return (bfbits(lo) & 0xffffu) | (bfbits(hi) << 16);
}
__device__ __forceinline__ float unplo(unsigned int w){ return __uint_as_float(w << 16); }
__device__ __forceinline__ float unphi(unsigned int w){ return __uint_as_float(w & 0xffff0000u); }
__device__ __forceinline__ float b2f(unsigned short s){ return __uint_as_float(((unsigned int)s) << 16); }
__device__ __forceinline__ unsigned short f2b(float x){ return (unsigned short)bfbits(x); }

__device__ __forceinline__ void atomAddF(float* p, float v){
  unsafeAtomicAdd(p, v);  // HW global_atomic_add_f32 on gfx950
}

// ---------------------------------------------------------------------------
// Kernel 1: per-node first-layer tables.
//  table 0: Aes = h @ We_w1[0:128]   + t @ We_w1[273:305] + We_b1
//  table 1: Aed = h @ We_w1[128:256]
//  table 2: Axs = h @ Wx_w1[0:128]   + t @ Wx_w1[272:304] + Wx_b1
//  table 3: Axd = h @ Wx_w1[128:256]
// ---------------------------------------------------------------------------
__global__ void __launch_bounds__(256) k_pre(
    const float* __restrict__ h, const float* __restrict__ t_emb,
    const float* __restrict__ We_w1, const float* __restrict__ We_b1,
    const float* __restrict__ Wx_w1, const float* __restrict__ Wx_b1,
    unsigned short* __restrict__ Aes, unsigned short* __restrict__ Aed,
    unsigned short* __restrict__ Axs, unsigned short* __restrict__ Axd,
    int N)
{
  const int table = blockIdx.y;                 // 0..3
  const bool isE   = (table <= 1);
  const bool isSrc = (table == 0 || table == 2);
  const float* W    = isE ? We_w1 : Wx_w1;
  const float* bias = (table == 0) ? We_b1 : (table == 2 ? Wx_b1 : nullptr);
  unsigned short* out = (table == 0) ? Aes : (table == 1) ? Aed : (table == 2) ? Axs : Axd;
  const int K = isSrc ? (HD + TD) : HD;
  const int tRowBase = isE ? 273 : 272;

  __shared__ unsigned int Wp[(HD + TD) * 64];   // 40KB max, bf16 pairs (c, c+64)

  for (int i = threadIdx.x; i < K * 64; i += 256){
    int k = i >> 6, l = i & 63;
    int row = (k < HD) ? (isSrc ? k : (HD + k)) : (tRowBase + (k - HD));
    Wp[i] = packbf(W[row * HD + l], W[row * HD + l + 64]);
  }
  __syncthreads();

  const int lane = threadIdx.x & 63, wave = threadIdx.x >> 6;
  const int nw = gridDim.x * 4;
  const float bb0 = bias ? bias[lane]      : 0.f;
  const float bb1 = bias ? bias[lane + 64] : 0.f;

  for (int n = blockIdx.x * 4 + wave; n < N; n += nw){
    float f0 = h[(size_t)n * HD + lane];
    float f1 = h[(size_t)n * HD + 64 + lane];
    float f2 = (isSrc && lane < TD) ? t_emb[(size_t)n * TD + lane] : 0.f;
    float a0 = bb0, a1 = bb1;
    #pragma unroll
    for (int k = 0; k < 64; ++k){
      float fk = __shfl(f0, k);
      unsigned int w = Wp[k * 64 + lane];
      a0 = fmaf(fk, unplo(w), a0);
      a1 = fmaf(fk, unphi(w), a1);
    }
    #pragma unroll
    for (int k = 0; k < 64; ++k){
      float fk = __shfl(f1, k);
      unsigned int w = Wp[(64 + k) * 64 + lane];
      a0 = fmaf(fk, unplo(w), a0);
      a1 = fmaf(fk, unphi(w), a1);
    }
    if (isSrc){
      #pragma unroll
      for (int k = 0; k < TD; ++k){
        float fk = __shfl(f2, k);
        unsigned int w = Wp[(HD + k) * 64 + lane];
        a0 = fmaf(fk, unplo(w), a0);
        a1 = fmaf(fk, unphi(w), a1);
      }
    }
    out[(size_t)n * HD + lane]      = f2b(a0);
    out[(size_t)n * HD + 64 + lane] = f2b(a1);
  }
}

// ---------------------------------------------------------------------------
// Kernel 2: message path. wave-per-edge.
// pre = Aes[src] + Aed[dst] + dist_sq*We_w1[256] + ea @ We_w1[257:273]
// m   = silu(pre) @ We_w2 + We_b2;  m *= sigmoid(m.Watt_w + Watt_b)
// atomic scatter into msg_agg[dst]
// ---------------------------------------------------------------------------
__global__ void __launch_bounds__(256) k_edge_msg(
    const int* __restrict__ ei, const float* __restrict__ x,
    const float* __restrict__ ea,
    const unsigned short* __restrict__ Aes, const unsigned short* __restrict__ Aed,
    const float* __restrict__ We_w1, const float* __restrict__ We_w2,
    const float* __restrict__ We_b2, const float* __restrict__ Watt_w,
    const float* __restrict__ Watt_b, float* __restrict__ msg_agg,
    int Ecnt)
{
  __shared__ unsigned int W2p[HD * 64];   // 32KB bf16 pairs
  __shared__ float ush[4][HD];
  for (int i = threadIdx.x; i < HD * 64; i += 256){
    int k = i >> 6, l = i & 63;
    W2p[i] = packbf(We_w2[k * HD + l], We_w2[k * HD + l + 64]);
  }
  __syncthreads();

  const int lane = threadIdx.x & 63, wave = threadIdx.x >> 6;
  const int c0 = lane, c1 = lane + 64;
  const float wb0 = We_b2[c0], wb1 = We_b2[c1];
  const float wa0 = Watt_w[c0], wa1 = Watt_w[c1];
  const float attb = Watt_b[0];
  const float wd0 = We_w1[256 * HD + c0], wd1 = We_w1[256 * HD + c1];
  const int nw = gridDim.x * 4;

  for (int e = blockIdx.x * 4 + wave; e < Ecnt; e += nw){
    int s = ei[e], d = ei[Ecnt + e];
    float dx = x[s * 3 + 0] - x[d * 3 + 0];
    float dy = x[s * 3 + 1] - x[d * 3 + 1];
    float dz = x[s * 3 + 2] - x[d * 3 + 2];
    float dist = dx * dx + dy * dy + dz * dz;
    float eav = (lane < ED) ? ea[(size_t)e * ED + lane] : 0.f;

    float p0 = b2f(Aes[(size_t)s * HD + c0]) + b2f(Aed[(size_t)d * HD + c0]) + dist * wd0;
    float p1 = b2f(Aes[(size_t)s * HD + c1]) + b2f(Aed[(size_t)d * HD + c1]) + dist * wd1;
    #pragma unroll
    for (int k = 0; k < ED; ++k){
      float ek = __shfl(eav, k);
      p0 = fmaf(ek, We_w1[(257 + k) * HD + c0], p0);
      p1 = fmaf(ek, We_w1[(257 + k) * HD + c1], p1);
    }
    ush[wave][lane]      = siluf(p0);
    ush[wave][lane + 64] = siluf(p1);

    float m0 = wb0, m1 = wb1;
    #pragma unroll
    for (int k = 0; k < HD; ++k){
      float uk = ush[wave][k];
      unsigned int w = W2p[k * 64 + lane];
      m0 = fmaf(uk, unplo(w), m0);
      m1 = fmaf(uk, unphi(w), m1);
    }
    float t = fmaf(m0, wa0, m1 * wa1);
    #pragma unroll
    for (int off = 32; off > 0; off >>= 1) t += __shfl_xor(t, off);
    float att = 1.f / (1.f + __expf(-(t + attb)));
    m0 *= att; m1 *= att;
    atomAddF(&msg_agg[(size_t)d * HD + c0], m0);
    atomAddF(&msg_agg[(size_t)d * HD + c1], m1);
  }
}

// ---------------------------------------------------------------------------
// Kernel 3: coord path. wave-per-edge.
// pre = Axs[src] + Axd[dst] + ea @ Wx_w1[256:272]
// cw  = tanh( silu( silu(pre) @ Wx_w2 + Wx_b2 ) . Wx_w3 )
// xout[dst] += diff/(norm+1) * cw * 2.5
// ---------------------------------------------------------------------------
__global__ void __launch_bounds__(256) k_edge_coord(
    const int* __restrict__ ei, const float* __restrict__ x,
    const float* __restrict__ ea,
    const unsigned short* __restrict__ Axs, const unsigned short* __restrict__ Axd,
    const float* __restrict__ Wx_w1, const float* __restrict__ Wx_w2,
    const float* __restrict__ Wx_b2, const float* __restrict__ Wx_w3,
    float* __restrict__ xout, int Ecnt)
{
  __shared__ unsigned int W2p[HD * 64];
  __shared__ float vsh[4][HD];
  for (int i = threadIdx.x; i < HD * 64; i += 256){
    int k = i >> 6, l = i & 63;
    W2p[i] = packbf(Wx_w2[k * HD + l], Wx_w2[k * HD + l + 64]);
  }
  __syncthreads();

  const int lane = threadIdx.x & 63, wave = threadIdx.x >> 6;
  const int c0 = lane, c1 = lane + 64;
  const float xb0 = Wx_b2[c0], xb1 = Wx_b2[c1];
  const float w30 = Wx_w3[c0], w31 = Wx_w3[c1];
  const int nw = gridDim.x * 4;

  for (int e = blockIdx.x * 4 + wave; e < Ecnt; e += nw){
    int s = ei[e], d = ei[Ecnt + e];
    float dx = x[s * 3 + 0] - x[d * 3 + 0];
    float dy = x[s * 3 + 1] - x[d * 3 + 1];
    float dz = x[s * 3 + 2] - x[d * 3 + 2];
    float dist = dx * dx + dy * dy + dz * dz;
    float norm = sqrtf(dist + 1e-8f);
    float rs = 2.5f / (norm + 1.0f);      // COORDS_RANGE / (norm + NORM_CONSTANT)
    float eav = (lane < ED) ? ea[(size_t)e * ED + lane] : 0.f;

    float p0 = b2f(Axs[(size_t)s * HD + c0]) + b2f(Axd[(size_t)d * HD + c0]);
    float p1 = b2f(Axs[(size_t)s * HD + c1]) + b2f(Axd[(size_t)d * HD + c1]);
    #pragma unroll
    for (int k = 0; k < ED; ++k){
      float ek = __shfl(eav, k);
      p0 = fmaf(ek, Wx_w1[(256 + k) * HD + c0], p0);
      p1 = fmaf(ek, Wx_w1[(256 + k) * HD + c1], p1);
    }
    vsh[wave][lane]      = siluf(p0);
    vsh[wave][lane + 64] = siluf(p1);

    float q0 = xb0, q1 = xb1;
    #pragma unroll
    for (int k = 0; k < HD; ++k){
      float vk = vsh[wave][k];
      unsigned int w = W2p[k * 64 + lane];
      q0 = fmaf(vk, unplo(w), q0);
      q1 = fmaf(vk, unphi(w), q1);
    }
    q0 = siluf(q0); q1 = siluf(q1);
    float t = fmaf(q0, w30, q1 * w31);
    #pragma unroll
    for (int off = 32; off > 0; off >>= 1) t += __shfl_xor(t, off);
    float sc = tanhf(t) * rs;
    if (lane < 3){
      float comp = (lane == 0) ? dx : ((lane == 1) ? dy : dz);
      atomAddF(&xout[(size_t)d * 3 + lane], comp * sc);
    }
  }
}

// ---------------------------------------------------------------------------
// Kernel 4: z = silu([h, msg_agg] @ Wh_w1 + Wh_b1)   (wave-per-node)
// ---------------------------------------------------------------------------
__global__ void __launch_bounds__(256) k_h1(
    const float* __restrict__ h, const float* __restrict__ msg,
    const float* __restrict__ Wh_w1, const float* __restrict__ Wh_b1,
    float* __restrict__ z, int N)
{
  __shared__ unsigned int Wp[256 * 64];   // 64KB
  for (int i = threadIdx.x; i < 256 * 64; i += 256){
    int k = i >> 6, l = i & 63;
    Wp[i] = packbf(Wh_w1[k * HD + l], Wh_w1[k * HD + l + 64]);
  }
  __syncthreads();

  const int lane = threadIdx.x & 63, wave = threadIdx.x >> 6;
  const int nw = gridDim.x * 4;
  const float bb0 = Wh_b1[lane], bb1 = Wh_b1[lane + 64];

  for (int n = blockIdx.x * 4 + wave; n < N; n += nw){
    float f0 = h[(size_t)n * HD + lane];
    float f1 = h[(size_t)n * HD + 64 + lane];
    float f2 = msg[(size_t)n * HD + lane];
    float f3 = msg[(size_t)n * HD + 64 + lane];
    float a0 = bb0, a1 = bb1;
    #pragma unroll
    for (int k = 0; k < 64; ++k){
      float fk = __shfl(f0, k);
      unsigned int w = Wp[k * 64 + lane];
      a0 = fmaf(fk, unplo(w), a0); a1 = fmaf(fk, unphi(w), a1);
    }
    #pragma unroll
    for (int k = 0; k < 64; ++k){
      float fk = __shfl(f1, k);
      unsigned int w = Wp[(64 + k) * 64 + lane];
      a0 = fmaf(fk, unplo(w), a0); a1 = fmaf(fk, unphi(w), a1);
    }
    #pragma unroll
    for (int k = 0; k < 64; ++k){
      float fk = __shfl(f2, k);
      unsigned int w = Wp[(128 + k) * 64 + lane];
      a0 = fmaf(fk, unplo(w), a0); a1 = fmaf(fk, unphi(w), a1);
    }
    #pragma unroll
    for (int k = 0; k < 64; ++k){
      float fk = __shfl(f3, k);
      unsigned int w = Wp[(192 + k) * 64 + lane];
      a0 = fmaf(fk, unplo(w), a0); a1 = fmaf(fk, unphi(w), a1);
    }
    z[(size_t)n * HD + lane]      = siluf(a0);
    z[(size_t)n * HD + 64 + lane] = siluf(a1);
  }
}

// ---------------------------------------------------------------------------
// Kernel 5: hout = h + z @ Wh_w2 + Wh_b2   (wave-per-node)
// ---------------------------------------------------------------------------
__global__ void __launch_bounds__(256) k_h2(
    const float* __restrict__ h, const float* __restrict__ z,
    const float* __restrict__ Wh_w2, const float* __restrict__ Wh_b2,
    float* __restrict__ hout, int N)
{
  __shared__ unsigned int Wp[HD * 64];
  for (int i = threadIdx.x; i < HD * 64; i += 256){
    int k = i >> 6, l = i & 63;
    Wp[i] = packbf(Wh_w2[k * HD + l], Wh_w2[k * HD + l + 64]);
  }
  __syncthreads();

  const int lane = threadIdx.x & 63, wave = threadIdx.x >> 6;
  const int nw = gridDim.x * 4;
  const float bb0 = Wh_b2[lane], bb1 = Wh_b2[lane + 64];

  for (int n = blockIdx.x * 4 + wave; n < N; n += nw){
    float f0 = z[(size_t)n * HD + lane];
    float f1 = z[(size_t)n * HD + 64 + lane];
    float a0 = bb0, a1 = bb1;
    #pragma unroll
    for (int k = 0; k < 64; ++k){
      float fk = __shfl(f0, k);
      unsigned int w = Wp[k * 64 + lane];
      a0 = fmaf(fk, unplo(w), a0); a1 = fmaf(fk, unphi(w), a1);
    }
    #pragma unroll
    for (int k = 0; k < 64; ++k){
      float fk = __shfl(f1, k);
      unsigned int w = Wp[(64 + k) * 64 + lane];
      a0 = fmaf(fk, unplo(w), a0); a1 = fmaf(fk, unphi(w), a1);
    }
    hout[(size_t)n * HD + lane]      = h[(size_t)n * HD + lane]      + a0;
    hout[(size_t)n * HD + 64 + lane] = h[(size_t)n * HD + 64 + lane] + a1;
  }
}

extern "C" void kernel_launch(void* const* d_in, const int* in_sizes, int n_in,
                              void* d_out, int out_size, void* d_ws, size_t ws_size,
                              hipStream_t stream)
{
  const float* h      = (const float*)d_in[0];
  const float* x      = (const float*)d_in[1];
  const int*   ei     = (const int*)  d_in[2];
  const float* ea     = (const float*)d_in[3];
  const float* t_emb  = (const float*)d_in[4];
  const float* We_w1  = (const float*)d_in[5];
  const float* We_b1  = (const float*)d_in[6];
  const float* We_w2  = (const float*)d_in[7];
  const float* We_b2  = (const float*)d_in[8];
  const float* Watt_w = (const float*)d_in[9];
  const float* Watt_b = (const float*)d_in[10];
  const float* Wx_w1  = (const float*)d_in[11];
  const float* Wx_b1  = (const float*)d_in[12];
  const float* Wx_w2  = (const float*)d_in[13];
  const float* Wx_b2  = (const float*)d_in[14];
  const float* Wx_w3  = (const float*)d_in[15];
  const float* Wh_w1  = (const float*)d_in[16];
  const float* Wh_b1  = (const float*)d_in[17];
  const float* Wh_w2  = (const float*)d_in[18];
  const float* Wh_b2  = (const float*)d_in[19];

  const int N = in_sizes[0] / HD;
  const int E = in_sizes[2] / 2;

  char* ws = (char*)d_ws;
  unsigned short* Aes = (unsigned short*)ws;  ws += (size_t)N * HD * 2;
  unsigned short* Aed = (unsigned short*)ws;  ws += (size_t)N * HD * 2;
  unsigned short* Axs = (unsigned short*)ws;  ws += (size_t)N * HD * 2;
  unsigned short* Axd = (unsigned short*)ws;  ws += (size_t)N * HD * 2;
  float* msg_agg = (float*)ws;                ws += (size_t)N * HD * 4;
  float* z       = (float*)ws;                ws += (size_t)N * HD * 4;

  float* hout = (float*)d_out;
  float* xout = hout + (size_t)N * HD;

  hipMemsetAsync(msg_agg, 0, (size_t)N * HD * 4, stream);
  hipMemcpyAsync(xout, x, (size_t)N * 3 * 4, hipMemcpyDeviceToDevice, stream);

  dim3 gP(128, 4);
  k_pre<<<gP, 256, 0, stream>>>(h, t_emb, We_w1, We_b1, Wx_w1, Wx_b1,
                                Aes, Aed, Axs, Axd, N);
  k_edge_msg<<<2048, 256, 0, stream>>>(ei, x, ea, Aes, Aed, We_w1, We_w2, We_b2,
                                       Watt_w, Watt_b, msg_agg, E);
  k_edge_coord<<<2048, 256, 0, stream>>>(ei, x, ea, Axs, Axd, Wx_w1, Wx_w2, Wx_b2,
                                         Wx_w3, xout, E);
  k_h1<<<512, 256, 0, stream>>>(h, msg_agg, Wh_w1, Wh_b1, z, N);
  k_h2<<<512, 256, 0, stream>>>(h, z, Wh_w2, Wh_b2, hout, N);
}